// Round 8
// baseline (2351.763 us; speedup 1.0000x reference)
//
#include <hip/hip_runtime.h>
#include <hip/hip_bf16.h>
#include <cstdint>

#define CIN   128
#define COUT  256
#define BATCH 16
#define HH    64
#define WW    64
#define TH    32
#define TW    32
#define NT    (BATCH*TH*TW)   /* 16384 winograd tiles */
#define APQ   (COUT*CIN)      /* U plane: 32768 elems */
#define BPQ   (NT*CIN)        /* V plane: 2097152 elems */

typedef __bf16 bf16x8 __attribute__((ext_vector_type(8)));
typedef float  f32x4  __attribute__((ext_vector_type(4)));

__device__ __forceinline__ void gload16(const void* g, void* l) {
    __builtin_amdgcn_global_load_lds(
        (const __attribute__((address_space(1))) uint32_t*)g,
        (__attribute__((address_space(3))) uint32_t*)l, 16, 0, 0);
}

// ---------------------------------------------------------------------------
// Kernel 1: weight transform  U[pq][k][c] = (G w G^T)[p][q], bf16
// ---------------------------------------------------------------------------
__global__ __launch_bounds__(256) void wg_wtrans(const float* __restrict__ w,
                                                 __hip_bfloat16* __restrict__ U) {
    int idx = blockIdx.x * 256 + threadIdx.x;       // idx = k*CIN + c
    if (idx >= COUT * CIN) return;
    const float* wp = w + idx * 9;
    float g[3][3];
#pragma unroll
    for (int x = 0; x < 3; x++)
#pragma unroll
        for (int y = 0; y < 3; y++) g[x][y] = wp[x * 3 + y];

    float t[4][3];
#pragma unroll
    for (int y = 0; y < 3; y++) {
        t[0][y] = g[0][y];
        t[1][y] = 0.5f * (g[0][y] + g[1][y] + g[2][y]);
        t[2][y] = 0.5f * (g[0][y] - g[1][y] + g[2][y]);
        t[3][y] = g[2][y];
    }
#pragma unroll
    for (int p = 0; p < 4; p++) {
        float u0 = t[p][0];
        float u1 = 0.5f * (t[p][0] + t[p][1] + t[p][2]);
        float u2 = 0.5f * (t[p][0] - t[p][1] + t[p][2]);
        float u3 = t[p][2];
        U[(p * 4 + 0) * APQ + idx] = __float2bfloat16(u0);
        U[(p * 4 + 1) * APQ + idx] = __float2bfloat16(u1);
        U[(p * 4 + 2) * APQ + idx] = __float2bfloat16(u2);
        U[(p * 4 + 3) * APQ + idx] = __float2bfloat16(u3);
    }
}

// ---------------------------------------------------------------------------
// Kernel 2: input transform  V[pq][bij][c] = (BT d BT^T)[p][q], bf16
// ---------------------------------------------------------------------------
__global__ __launch_bounds__(1024) void wg_itrans(const float* __restrict__ X,
                                                  __hip_bfloat16* __restrict__ V) {
    __shared__ float lds[32 * 265];
    const int c0 = blockIdx.x * 32;
    const int i  = blockIdx.y;
    const int b  = blockIdx.z;
    const int tid = threadIdx.x;

    for (int t = tid; t < 32 * 4; t += 1024) {
        int cc = t >> 2, r = t & 3;
        lds[cc * 265 + r * 66 + 0]  = 0.f;
        lds[cc * 265 + r * 66 + 65] = 0.f;
    }
    for (int t = tid; t < 32 * 4 * 64; t += 1024) {
        int x = t & 63, r = (t >> 6) & 3, cc = t >> 8;
        int y = 2 * i - 1 + r;
        float v = 0.f;
        if (y >= 0 && y < HH) v = X[(((b * CIN) + (c0 + cc)) * HH + y) * WW + x];
        lds[cc * 265 + r * 66 + 1 + x] = v;
    }
    __syncthreads();

    const int c = tid & 31;
    const int j = tid >> 5;
    const float* base = &lds[c * 265 + 2 * j];

    float t0[4], t1[4], t2[4], t3[4];
#pragma unroll
    for (int y = 0; y < 4; y++) {
        float a  = base[0 * 66 + y];
        float bb = base[1 * 66 + y];
        float cc = base[2 * 66 + y];
        float dd = base[3 * 66 + y];
        t0[y] = a - cc;
        t1[y] = bb + cc;
        t2[y] = cc - bb;
        t3[y] = bb - dd;
    }
    float vm[4][4];
#pragma unroll
    for (int p = 0; p < 4; p++) {
        const float* tp = (p == 0) ? t0 : (p == 1) ? t1 : (p == 2) ? t2 : t3;
        vm[p][0] = tp[0] - tp[2];
        vm[p][1] = tp[1] + tp[2];
        vm[p][2] = tp[2] - tp[1];
        vm[p][3] = tp[1] - tp[3];
    }

    const int bij = b * (TH * TW) + i * TW + j;
    const int vo  = bij * CIN + (c0 + c);
#pragma unroll
    for (int p = 0; p < 4; p++)
#pragma unroll
        for (int q = 0; q < 4; q++)
            V[(size_t)(p * 4 + q) * BPQ + vo] = __float2bfloat16(vm[p][q]);
}

// ---------------------------------------------------------------------------
// Kernel 3: fused GEMM + output transform — merged slot, reg-prefetch.
// Block [128 kout x 128 bij], 512 thr = 8 waves (2m x 4n), wave tile 64x32.
// One slot per BK=64 (32 slots): 16 MFMA + 12 ds_read per wave between ONE
// barrier pair. kk0 fragments double-buffered in regs, prefetched during the
// previous slot's MFMA region; kk1 issued at slot top; counted lgkmcnt(6)
// (FIFO completion) separates the groups. Counted vmcnt(8), depth-3 staging,
// 4 LDS buffers. Fold in the wait-slot, fully unrolled (+/-1 compile-time).
// ---------------------------------------------------------------------------
#define ABYTES 16384
#define BUFSZ  32768

__global__ __launch_bounds__(512, 2) void wg_gemm8(const __hip_bfloat16* __restrict__ U,
                                                   const __hip_bfloat16* __restrict__ V,
                                                   const float* __restrict__ bias,
                                                   float* __restrict__ out) {
    __shared__ char lds[4 * BUFSZ];      // 128 KB

    // bijective XCD swizzle (256 % 8 == 0): 32 consecutive wg per XCD
    int orig = blockIdx.x;
    int wgid = (orig & 7) * 32 + (orig >> 3);
    const int mt = wgid & 1, nt = wgid >> 1;
    const int m0 = mt * 128, n0 = nt * 128;

    const int tid  = threadIdx.x;
    const int lane = tid & 63;
    const int wave = tid >> 6;
    const int wm = wave >> 2, wn = wave & 3;

    // staging: chunk c holds tile granule (row R=c>>3, gran G=(c&7)^(R&7))
    const __hip_bfloat16* pa[2];
    const __hip_bfloat16* pb[2];
    int ldsA[2], ldsB[2];
#pragma unroll
    for (int ch = 0; ch < 2; ch++) {
        int c = ch * 512 + tid;
        int R = c >> 3;
        int G = (c & 7) ^ (R & 7);
        pa[ch] = U + (m0 + R) * CIN + G * 8;
        pb[ch] = V + (size_t)(n0 + R) * CIN + G * 8;
        ldsA[ch] = c * 16;
        ldsB[ch] = ABYTES + c * 16;
    }

    // ds_read offsets: row r, k-granule g -> byte r*128 + ((g ^ (r&7))<<4)
    const int la = lane & 15, hq = lane >> 4, l7 = lane & 7;
    int aoff[2], boff[2];
#pragma unroll
    for (int kk = 0; kk < 2; kk++) {
        int g = (kk * 4 + hq) ^ l7;
        aoff[kk] = (wm * 64 + la) * 128 + (g << 4);
        boff[kk] = ABYTES + (wn * 32 + la) * 128 + (g << 4);
    }

    f32x4 yac[2][2][4][2];
#pragma unroll
    for (int x = 0; x < 2; x++)
#pragma unroll
        for (int y = 0; y < 2; y++)
#pragma unroll
            for (int mi = 0; mi < 4; mi++)
#pragma unroll
                for (int nj = 0; nj < 2; nj++) yac[x][y][mi][nj] = (f32x4){0.f, 0.f, 0.f, 0.f};
    f32x4 mac[4][2];

    bf16x8 a0[2][4], b0[2][2];           // kk0 sets (double-buffered, [t&1])
    bf16x8 a1[4],    b1[2];              // kk1 set (per-slot)

    auto stage = [&](int s) {
        char* sb = lds + (s & 3) * BUFSZ;
        const int pq = s >> 1, kb = (s & 1) * 64;
        gload16(pa[0] + pq * APQ + kb, sb + ldsA[0]);
        gload16(pa[1] + pq * APQ + kb, sb + ldsA[1]);
        gload16(pb[0] + (size_t)pq * BPQ + kb, sb + ldsB[0]);
        gload16(pb[1] + (size_t)pq * BPQ + kb, sb + ldsB[1]);
    };
    auto rd0 = [&](int t, int set) {     // kk0 fragments of buf t
        const char* rb = lds + (t & 3) * BUFSZ;
#pragma unroll
        for (int mi = 0; mi < 4; mi++)
            a0[set][mi] = *reinterpret_cast<const bf16x8*>(rb + aoff[0] + mi * 2048);
#pragma unroll
        for (int nj = 0; nj < 2; nj++)
            b0[set][nj] = *reinterpret_cast<const bf16x8*>(rb + boff[0] + nj * 2048);
    };
    auto rd1 = [&](int t) {              // kk1 fragments of buf t
        const char* rb = lds + (t & 3) * BUFSZ;
#pragma unroll
        for (int mi = 0; mi < 4; mi++)
            a1[mi] = *reinterpret_cast<const bf16x8*>(rb + aoff[1] + mi * 2048);
#pragma unroll
        for (int nj = 0; nj < 2; nj++)
            b1[nj] = *reinterpret_cast<const bf16x8*>(rb + boff[1] + nj * 2048);
    };

    // prologue: 3 stages in flight, kk0 regs for slot 0
    stage(0); stage(1); stage(2);
    asm volatile("s_waitcnt vmcnt(8)");  // stage 0 complete
    __builtin_amdgcn_s_barrier();
    rd0(0, 0);

#pragma unroll
    for (int t = 0; t < 32; ++t) {
        if (t <= 28) stage(t + 3);
        if (t >= 2 && (t & 1) == 0) {    // fold pq = t/2-1 (overlaps waits)
            const int pq = (t >> 1) - 1;
            const int p = pq >> 2, q = pq & 3;
            constexpr float W0[4] = {1.f, 1.f, 1.f, 0.f};
            constexpr float W1[4] = {0.f, 1.f, -1.f, -1.f};
#pragma unroll
            for (int mi = 0; mi < 4; mi++)
#pragma unroll
                for (int nj = 0; nj < 2; nj++) {
                    f32x4 m = mac[mi][nj];
                    if (W0[p] * W0[q] != 0.f) yac[0][0][mi][nj] += W0[p] * W0[q] * m;
                    if (W0[p] * W1[q] != 0.f) yac[0][1][mi][nj] += W0[p] * W1[q] * m;
                    if (W1[p] * W0[q] != 0.f) yac[1][0][mi][nj] += W1[p] * W0[q] * m;
                    if (W1[p] * W1[q] != 0.f) yac[1][1][mi][nj] += W1[p] * W1[q] * m;
                }
        }
        if (t <= 28)      asm volatile("s_waitcnt vmcnt(8)");
        else if (t == 29) asm volatile("s_waitcnt vmcnt(4)");
        else if (t == 30) asm volatile("s_waitcnt vmcnt(0)");
        __builtin_amdgcn_s_barrier();
        __builtin_amdgcn_sched_barrier(0);

        rd1(t);                          // kk1 reads (buf t published)
        asm volatile("s_waitcnt lgkmcnt(6)");   // kk0 set ready (FIFO)
        __builtin_amdgcn_sched_barrier(0);

        __builtin_amdgcn_s_setprio(1);
        const int s = t & 1;
        const bool init = (t & 1) == 0;
#pragma unroll
        for (int mi = 0; mi < 4; mi++)
#pragma unroll
            for (int nj = 0; nj < 2; nj++)
                mac[mi][nj] = __builtin_amdgcn_mfma_f32_16x16x32_bf16(
                    a0[s][mi], b0[s][nj],
                    init ? (f32x4){0.f, 0.f, 0.f, 0.f} : mac[mi][nj], 0, 0, 0);
        __builtin_amdgcn_s_setprio(0);

        if (t <= 30) rd0(t + 1, (t + 1) & 1);   // prefetch next slot's kk0
        asm volatile("s_waitcnt lgkmcnt(6)");   // kk1 set ready (FIFO)
        __builtin_amdgcn_sched_barrier(0);

        __builtin_amdgcn_s_setprio(1);
#pragma unroll
        for (int mi = 0; mi < 4; mi++)
#pragma unroll
            for (int nj = 0; nj < 2; nj++)
                mac[mi][nj] = __builtin_amdgcn_mfma_f32_16x16x32_bf16(
                    a1[mi], b1[nj], mac[mi][nj], 0, 0, 0);
        __builtin_amdgcn_s_setprio(0);
        __builtin_amdgcn_sched_barrier(0);
        __builtin_amdgcn_s_barrier();
    }

    { // fold pq = 15
        constexpr int p = 3, q = 3;      // W0=0, W1=-1 for both
#pragma unroll
        for (int mi = 0; mi < 4; mi++)
#pragma unroll
            for (int nj = 0; nj < 2; nj++)
                yac[1][1][mi][nj] += mac[mi][nj];   // (-1)*(-1)
        (void)p; (void)q;
    }

    // ---- writeout: D frag: col(bij)=lane&15, row(kout)=(lane>>4)*4+r ----
    const int lr = lane & 15, rg = lane >> 4;
#pragma unroll
    for (int mi = 0; mi < 4; mi++) {
#pragma unroll
        for (int r = 0; r < 4; r++) {
            const int kout = m0 + wm * 64 + mi * 16 + rg * 4 + r;
            const float bvv = bias[kout];
#pragma unroll
            for (int nj = 0; nj < 2; nj++) {
                const int bij = n0 + wn * 32 + nj * 16 + lr;
                const int bb = bij >> 10, ti = (bij >> 5) & 31, tj = bij & 31;
                float* op = out + (((size_t)bb * COUT + kout) * HH + 2 * ti) * WW + 2 * tj;
                *reinterpret_cast<float2*>(op) =
                    make_float2(yac[0][0][mi][nj][r] + bvv, yac[0][1][mi][nj][r] + bvv);
                *reinterpret_cast<float2*>(op + WW) =
                    make_float2(yac[1][0][mi][nj][r] + bvv, yac[1][1][mi][nj][r] + bvv);
            }
        }
    }
}

// ---------------------------------------------------------------------------
extern "C" void kernel_launch(void* const* d_in, const int* in_sizes, int n_in,
                              void* d_out, int out_size, void* d_ws, size_t ws_size,
                              hipStream_t stream) {
    const float* X    = (const float*)d_in[0];
    const float* w    = (const float*)d_in[1];
    const float* bias = (const float*)d_in[2];
    float* out        = (float*)d_out;

    __hip_bfloat16* U = (__hip_bfloat16*)d_ws;                       // 1 MB
    __hip_bfloat16* V = (__hip_bfloat16*)((char*)d_ws + (1u << 20)); // 64 MB

    wg_wtrans<<<(COUT * CIN + 255) / 256, 256, 0, stream>>>(w, U);
    wg_itrans<<<dim3(CIN / 32, TH, BATCH), 1024, 0, stream>>>(X, V);
    wg_gemm8<<<(COUT / 128) * (NT / 128), 512, 0, stream>>>(U, V, bias, out);
}

// Round 9
// 67.412 us; speedup vs baseline: 34.8863x; 34.8863x over previous
//
#include <hip/hip_runtime.h>
#include <hip/hip_bf16.h>
#include <cstdint>

#define CIN   128
#define COUT  256
#define BATCH 16
#define HH    64
#define WW    64
#define TH    32
#define TW    32
#define NT    (BATCH*TH*TW)   /* 16384 winograd tiles */
#define APQ   (COUT*CIN)      /* U plane: 32768 elems */
#define BPQ   (NT*CIN)        /* V plane: 2097152 elems */

typedef __bf16 bf16x8 __attribute__((ext_vector_type(8)));
typedef float  f32x4  __attribute__((ext_vector_type(4)));

__device__ __forceinline__ void gload16(const void* g, void* l) {
    __builtin_amdgcn_global_load_lds(
        (const __attribute__((address_space(1))) uint32_t*)g,
        (__attribute__((address_space(3))) uint32_t*)l, 16, 0, 0);
}

// ---------------------------------------------------------------------------
// Kernel 1: weight transform  U[pq][k][c] = (G w G^T)[p][q], bf16
// ---------------------------------------------------------------------------
__global__ __launch_bounds__(256) void wg_wtrans(const float* __restrict__ w,
                                                 __hip_bfloat16* __restrict__ U) {
    int idx = blockIdx.x * 256 + threadIdx.x;       // idx = k*CIN + c
    if (idx >= COUT * CIN) return;
    const float* wp = w + idx * 9;
    float g[3][3];
#pragma unroll
    for (int x = 0; x < 3; x++)
#pragma unroll
        for (int y = 0; y < 3; y++) g[x][y] = wp[x * 3 + y];

    float t[4][3];
#pragma unroll
    for (int y = 0; y < 3; y++) {
        t[0][y] = g[0][y];
        t[1][y] = 0.5f * (g[0][y] + g[1][y] + g[2][y]);
        t[2][y] = 0.5f * (g[0][y] - g[1][y] + g[2][y]);
        t[3][y] = g[2][y];
    }
#pragma unroll
    for (int p = 0; p < 4; p++) {
        float u0 = t[p][0];
        float u1 = 0.5f * (t[p][0] + t[p][1] + t[p][2]);
        float u2 = 0.5f * (t[p][0] - t[p][1] + t[p][2]);
        float u3 = t[p][2];
        U[(p * 4 + 0) * APQ + idx] = __float2bfloat16(u0);
        U[(p * 4 + 1) * APQ + idx] = __float2bfloat16(u1);
        U[(p * 4 + 2) * APQ + idx] = __float2bfloat16(u2);
        U[(p * 4 + 3) * APQ + idx] = __float2bfloat16(u3);
    }
}

// ---------------------------------------------------------------------------
// Kernel 2: input transform  V[pq][bij][c] = (BT d BT^T)[p][q], bf16
// ---------------------------------------------------------------------------
__global__ __launch_bounds__(1024) void wg_itrans(const float* __restrict__ X,
                                                  __hip_bfloat16* __restrict__ V) {
    __shared__ float lds[32 * 265];
    const int c0 = blockIdx.x * 32;
    const int i  = blockIdx.y;
    const int b  = blockIdx.z;
    const int tid = threadIdx.x;

    for (int t = tid; t < 32 * 4; t += 1024) {
        int cc = t >> 2, r = t & 3;
        lds[cc * 265 + r * 66 + 0]  = 0.f;
        lds[cc * 265 + r * 66 + 65] = 0.f;
    }
    for (int t = tid; t < 32 * 4 * 64; t += 1024) {
        int x = t & 63, r = (t >> 6) & 3, cc = t >> 8;
        int y = 2 * i - 1 + r;
        float v = 0.f;
        if (y >= 0 && y < HH) v = X[(((b * CIN) + (c0 + cc)) * HH + y) * WW + x];
        lds[cc * 265 + r * 66 + 1 + x] = v;
    }
    __syncthreads();

    const int c = tid & 31;
    const int j = tid >> 5;
    const float* base = &lds[c * 265 + 2 * j];

    float t0[4], t1[4], t2[4], t3[4];
#pragma unroll
    for (int y = 0; y < 4; y++) {
        float a  = base[0 * 66 + y];
        float bb = base[1 * 66 + y];
        float cc = base[2 * 66 + y];
        float dd = base[3 * 66 + y];
        t0[y] = a - cc;
        t1[y] = bb + cc;
        t2[y] = cc - bb;
        t3[y] = bb - dd;
    }
    float vm[4][4];
#pragma unroll
    for (int p = 0; p < 4; p++) {
        const float* tp = (p == 0) ? t0 : (p == 1) ? t1 : (p == 2) ? t2 : t3;
        vm[p][0] = tp[0] - tp[2];
        vm[p][1] = tp[1] + tp[2];
        vm[p][2] = tp[2] - tp[1];
        vm[p][3] = tp[1] - tp[3];
    }

    const int bij = b * (TH * TW) + i * TW + j;
    const int vo  = bij * CIN + (c0 + c);
#pragma unroll
    for (int p = 0; p < 4; p++)
#pragma unroll
        for (int q = 0; q < 4; q++)
            V[(size_t)(p * 4 + q) * BPQ + vo] = __float2bfloat16(vm[p][q]);
}

// ---------------------------------------------------------------------------
// Kernel 3: fused GEMM + output transform — merged slot, STATIC reg sets.
// Block [128 kout x 128 bij], 512 thr = 8 waves (2m x 4n), wave tile 64x32.
// One slot per BK=64 (32 slots): 16 MFMA + 12 ds_read between ONE barrier
// pair. kk0 fragments in named double-buffer sets aX/bX <-> aY/bY (rule 20:
// every register-array index compile-time). kk1 set a1/b1 read at slot top.
// Counted lgkmcnt(6) separates the FIFO groups; counted vmcnt(8); 4 LDS
// buffers, depth-3 staging. Fold = wave-uniform branches, avg 2.25 planes.
// ---------------------------------------------------------------------------
#define ABYTES 16384
#define BUFSZ  32768

__global__ __launch_bounds__(512, 2) void wg_gemm9(const __hip_bfloat16* __restrict__ U,
                                                   const __hip_bfloat16* __restrict__ V,
                                                   const float* __restrict__ bias,
                                                   float* __restrict__ out) {
    __shared__ char lds[4 * BUFSZ];      // 128 KB

    // bijective XCD swizzle (256 % 8 == 0): 32 consecutive wg per XCD
    int orig = blockIdx.x;
    int wgid = (orig & 7) * 32 + (orig >> 3);
    const int mt = wgid & 1, nt = wgid >> 1;
    const int m0 = mt * 128, n0 = nt * 128;

    const int tid  = threadIdx.x;
    const int lane = tid & 63;
    const int wave = tid >> 6;
    const int wm = wave >> 2, wn = wave & 3;

    // staging: chunk c holds tile granule (row R=c>>3, gran G=(c&7)^(R&7))
    const __hip_bfloat16* pa[2];
    const __hip_bfloat16* pb[2];
    int ldsA[2], ldsB[2];
#pragma unroll
    for (int ch = 0; ch < 2; ch++) {
        int c = ch * 512 + tid;
        int R = c >> 3;
        int G = (c & 7) ^ (R & 7);
        pa[ch] = U + (m0 + R) * CIN + G * 8;
        pb[ch] = V + (size_t)(n0 + R) * CIN + G * 8;
        ldsA[ch] = c * 16;
        ldsB[ch] = ABYTES + c * 16;
    }

    // ds_read offsets: row r, k-granule g -> byte r*128 + ((g ^ (r&7))<<4)
    const int la = lane & 15, hq = lane >> 4, l7 = lane & 7;
    int aoff[2], boff[2];
#pragma unroll
    for (int kk = 0; kk < 2; kk++) {
        int g = (kk * 4 + hq) ^ l7;
        aoff[kk] = (wm * 64 + la) * 128 + (g << 4);
        boff[kk] = ABYTES + (wn * 32 + la) * 128 + (g << 4);
    }

    f32x4 yac[2][2][4][2];
#pragma unroll
    for (int x = 0; x < 2; x++)
#pragma unroll
        for (int y = 0; y < 2; y++)
#pragma unroll
            for (int mi = 0; mi < 4; mi++)
#pragma unroll
                for (int nj = 0; nj < 2; nj++) yac[x][y][mi][nj] = (f32x4){0.f, 0.f, 0.f, 0.f};
    f32x4 mac[4][2];
    const f32x4 fz = (f32x4){0.f, 0.f, 0.f, 0.f};

    bf16x8 aX[4], bX[2], aY[4], bY[2];   // kk0 double-buffer (named sets)
    bf16x8 a1[4], b1[2];                 // kk1 per-slot set

    auto stage = [&](int s) {
        char* sb = lds + (s & 3) * BUFSZ;
        const int pq = s >> 1, kb = (s & 1) * 64;
        gload16(pa[0] + pq * APQ + kb, sb + ldsA[0]);
        gload16(pa[1] + pq * APQ + kb, sb + ldsA[1]);
        gload16(pb[0] + (size_t)pq * BPQ + kb, sb + ldsB[0]);
        gload16(pb[1] + (size_t)pq * BPQ + kb, sb + ldsB[1]);
    };

    auto fold = [&](int pq) {            // M[pq] -> Y planes, uniform branches
        const int p = pq >> 2, q = pq & 3;
        const float s1p = (p >= 2) ? -1.f : 1.f;
        const float s1q = (q >= 2) ? -1.f : 1.f;
        if (p != 3 && q != 3) {
#pragma unroll
            for (int mi = 0; mi < 4; mi++)
#pragma unroll
                for (int nj = 0; nj < 2; nj++) yac[0][0][mi][nj] += mac[mi][nj];
        }
        if (p != 3 && q != 0) {
#pragma unroll
            for (int mi = 0; mi < 4; mi++)
#pragma unroll
                for (int nj = 0; nj < 2; nj++) yac[0][1][mi][nj] += s1q * mac[mi][nj];
        }
        if (p != 0 && q != 3) {
#pragma unroll
            for (int mi = 0; mi < 4; mi++)
#pragma unroll
                for (int nj = 0; nj < 2; nj++) yac[1][0][mi][nj] += s1p * mac[mi][nj];
        }
        if (p != 0 && q != 0) {
            const float s11 = s1p * s1q;
#pragma unroll
            for (int mi = 0; mi < 4; mi++)
#pragma unroll
                for (int nj = 0; nj < 2; nj++) yac[1][1][mi][nj] += s11 * mac[mi][nj];
        }
    };

#define SLOT(T, AIN, BIN, AOUT, BOUT, VMC, STG, PRE, INIT, LGK2)              \
    {                                                                          \
        const int t_ = (T);                                                    \
        if (STG) stage(t_ + 3);                                                \
        if ((VMC) == 8)      asm volatile("s_waitcnt vmcnt(8)");               \
        else if ((VMC) == 4) asm volatile("s_waitcnt vmcnt(4)");               \
        else if ((VMC) == 0) asm volatile("s_waitcnt vmcnt(0)");               \
        __builtin_amdgcn_s_barrier();                                          \
        __builtin_amdgcn_sched_barrier(0);                                     \
        {                                                                      \
            const char* rb_ = lds + (t_ & 3) * BUFSZ;                          \
            _Pragma("unroll")                                                  \
            for (int mi = 0; mi < 4; mi++)                                     \
                a1[mi] = *reinterpret_cast<const bf16x8*>(rb_ + aoff[1] + mi * 2048); \
            _Pragma("unroll")                                                  \
            for (int nj = 0; nj < 2; nj++)                                     \
                b1[nj] = *reinterpret_cast<const bf16x8*>(rb_ + boff[1] + nj * 2048); \
        }                                                                      \
        __builtin_amdgcn_sched_barrier(0);                                     \
        asm volatile("s_waitcnt lgkmcnt(6)");                                  \
        __builtin_amdgcn_sched_barrier(0);                                     \
        __builtin_amdgcn_s_setprio(1);                                         \
        _Pragma("unroll")                                                      \
        for (int mi = 0; mi < 4; mi++)                                         \
            _Pragma("unroll")                                                  \
            for (int nj = 0; nj < 2; nj++)                                     \
                mac[mi][nj] = __builtin_amdgcn_mfma_f32_16x16x32_bf16(         \
                    AIN[mi], BIN[nj], (INIT) ? fz : mac[mi][nj], 0, 0, 0);     \
        __builtin_amdgcn_s_setprio(0);                                         \
        if (PRE) {                                                             \
            const char* rb2_ = lds + ((t_ + 1) & 3) * BUFSZ;                   \
            _Pragma("unroll")                                                  \
            for (int mi = 0; mi < 4; mi++)                                     \
                AOUT[mi] = *reinterpret_cast<const bf16x8*>(rb2_ + aoff[0] + mi * 2048); \
            _Pragma("unroll")                                                  \
            for (int nj = 0; nj < 2; nj++)                                     \
                BOUT[nj] = *reinterpret_cast<const bf16x8*>(rb2_ + boff[0] + nj * 2048); \
        }                                                                      \
        __builtin_amdgcn_sched_barrier(0);                                     \
        if ((LGK2) == 6) asm volatile("s_waitcnt lgkmcnt(6)");                 \
        else             asm volatile("s_waitcnt lgkmcnt(0)");                 \
        __builtin_amdgcn_sched_barrier(0);                                     \
        __builtin_amdgcn_s_setprio(1);                                         \
        _Pragma("unroll")                                                      \
        for (int mi = 0; mi < 4; mi++)                                         \
            _Pragma("unroll")                                                  \
            for (int nj = 0; nj < 2; nj++)                                     \
                mac[mi][nj] = __builtin_amdgcn_mfma_f32_16x16x32_bf16(         \
                    a1[mi], b1[nj], mac[mi][nj], 0, 0, 0);                     \
        __builtin_amdgcn_s_setprio(0);                                         \
        __builtin_amdgcn_sched_barrier(0);                                     \
        __builtin_amdgcn_s_barrier();                                          \
    }

    // prologue: 3 stages in flight; kk0 regs for slot 0 -> set X
    stage(0); stage(1); stage(2);
    asm volatile("s_waitcnt vmcnt(8)");  // stage 0 complete
    __builtin_amdgcn_s_barrier();
    {
        const char* rb_ = lds;
#pragma unroll
        for (int mi = 0; mi < 4; mi++)
            aX[mi] = *reinterpret_cast<const bf16x8*>(rb_ + aoff[0] + mi * 2048);
#pragma unroll
        for (int nj = 0; nj < 2; nj++)
            bX[nj] = *reinterpret_cast<const bf16x8*>(rb_ + boff[0] + nj * 2048);
    }

    for (int tt = 0; tt < 28; tt += 2) {
        if (tt >= 2) fold((tt >> 1) - 1);
        SLOT(tt,     aX, bX, aY, bY, 8, true, true, true,  6)
        SLOT(tt + 1, aY, bY, aX, bX, 8, true, true, false, 6)
    }
    fold(13);
    SLOT(28, aX, bX, aY, bY, 8,  true,  true,  true,  6)
    SLOT(29, aY, bY, aX, bX, 4,  false, true,  false, 6)
    fold(14);
    SLOT(30, aX, bX, aY, bY, 0,  false, true,  true,  6)
    SLOT(31, aY, bY, aX, bX, -1, false, false, false, 0)
    fold(15);

#undef SLOT

    // ---- writeout: D frag: col(bij)=lane&15, row(kout)=(lane>>4)*4+r ----
    const int lr = lane & 15, rg = lane >> 4;
#pragma unroll
    for (int mi = 0; mi < 4; mi++) {
#pragma unroll
        for (int r = 0; r < 4; r++) {
            const int kout = m0 + wm * 64 + mi * 16 + rg * 4 + r;
            const float bvv = bias[kout];
#pragma unroll
            for (int nj = 0; nj < 2; nj++) {
                const int bij = n0 + wn * 32 + nj * 16 + lr;
                const int bb = bij >> 10, ti = (bij >> 5) & 31, tj = bij & 31;
                float* op = out + (((size_t)bb * COUT + kout) * HH + 2 * ti) * WW + 2 * tj;
                *reinterpret_cast<float2*>(op) =
                    make_float2(yac[0][0][mi][nj][r] + bvv, yac[0][1][mi][nj][r] + bvv);
                *reinterpret_cast<float2*>(op + WW) =
                    make_float2(yac[1][0][mi][nj][r] + bvv, yac[1][1][mi][nj][r] + bvv);
            }
        }
    }
}

// ---------------------------------------------------------------------------
extern "C" void kernel_launch(void* const* d_in, const int* in_sizes, int n_in,
                              void* d_out, int out_size, void* d_ws, size_t ws_size,
                              hipStream_t stream) {
    const float* X    = (const float*)d_in[0];
    const float* w    = (const float*)d_in[1];
    const float* bias = (const float*)d_in[2];
    float* out        = (float*)d_out;

    __hip_bfloat16* U = (__hip_bfloat16*)d_ws;                       // 1 MB
    __hip_bfloat16* V = (__hip_bfloat16*)((char*)d_ws + (1u << 20)); // 64 MB

    wg_wtrans<<<(COUT * CIN + 255) / 256, 256, 0, stream>>>(w, U);
    wg_itrans<<<dim3(CIN / 32, TH, BATCH), 1024, 0, stream>>>(X, V);
    wg_gemm9<<<(COUT / 128) * (NT / 128), 512, 0, stream>>>(U, V, bias, out);
}